// Round 19
// baseline (5029.469 us; speedup 1.0000x reference)
//
#include <hip/hip_runtime.h>
#include <hip/hip_bf16.h>

#define VOCAB  128
#define EMBED  256
#define HIDDEN 1024
#define SEQ    512
#define BATCH  128
#define NGCOL  4096   // 4*HIDDEN, gate-interleaved packed cols (p = 4*j + g)
#define NCOL   4224   // + VOCAB classifier cols appended

typedef short s8v __attribute__((ext_vector_type(8)));  // 8 bf16
typedef float f4  __attribute__((ext_vector_type(4)));
typedef unsigned u4v __attribute__((ext_vector_type(4)));

__device__ __forceinline__ unsigned short f2bf(float f) {
    unsigned u = __float_as_uint(f);
    u += 0x7fffu + ((u >> 16) & 1u);
    return (unsigned short)(u >> 16);
}
__device__ __forceinline__ float sigm(float x) { return 1.f / (1.f + __expf(-x)); }
__device__ __forceinline__ float tanh_(float x) {
    x = fminf(fmaxf(x, -15.f), 15.f);
    float e = __expf(2.f * x);
    return (e - 1.f) / (e + 1.f);
}

// write-through stores (sc0 sc1): ack at the coherent point, never dirty the XCD L2.
__device__ __forceinline__ void st_dword_wt(float* p, float v) {
    asm volatile("global_store_dword %0, %1, off sc0 sc1" :: "v"(p), "v"(v) : "memory");
}
__device__ __forceinline__ void st_b128_wt(unsigned short* p, u4v v) {
    asm volatile("global_store_dwordx4 %0, %1, off sc0 sc1" :: "v"(p), "v"(v) : "memory");
}
__device__ __forceinline__ void st_flag_wt(unsigned* p, unsigned v) {
    asm volatile("global_store_dword %0, %1, off sc0 sc1" :: "v"(p), "v"(v) : "memory");
}

// ---- pack gate weights, coalesced ----
__global__ void k_pack(const float* __restrict__ Wi, const float* __restrict__ Wf,
                       const float* __restrict__ Wg, const float* __restrict__ Wo,
                       unsigned short* __restrict__ Bp) {
    int idx = blockIdx.x * 256 + threadIdx.x;   // 1M threads
    int k = idx >> 10, j = idx & 1023;
    int src = k * HIDDEN + j;
    size_t base = ((size_t)(j >> 2) * 128 + (k >> 3)) * 128 + ((j & 3) << 5) + (k & 7);
    Bp[base]      = f2bf(Wi[src]);
    Bp[base + 8]  = f2bf(Wf[src]);
    Bp[base + 16] = f2bf(Wg[src]);
    Bp[base + 24] = f2bf(Wo[src]);
}

__global__ void k_packc(const float* __restrict__ Wcls, unsigned short* __restrict__ Bp) {
    int idx = blockIdx.x * 256 + threadIdx.x;   // 131072 threads: (v, k)
    int v = idx >> 10, k = idx & 1023;
    int p = NGCOL + v;
    Bp[((size_t)(p >> 4) * 128 + (k >> 3)) * 128 + (p & 15) * 8 + (k & 7)] = f2bf(Wcls[v * HIDDEN + k]);
}

__global__ void k_proj(const float* __restrict__ emb,
                       const float* __restrict__ Wix, const float* __restrict__ Wfx,
                       const float* __restrict__ Wgx, const float* __restrict__ Wox,
                       const float* __restrict__ bi,  const float* __restrict__ bf_,
                       const float* __restrict__ bg,  const float* __restrict__ bo,
                       float* __restrict__ proj) {
    int idx = blockIdx.x * 256 + threadIdx.x;   // 524288 threads: (v, g, j)
    int j = idx & 1023;
    int g = (idx >> 10) & 3;
    int v = idx >> 12;
    const float* W  = (g == 0) ? Wix : (g == 1) ? Wfx : (g == 2) ? Wgx : Wox;
    const float* bb = (g == 0) ? bi  : (g == 1) ? bf_ : (g == 2) ? bg  : bo;
    float s = bb[j];
    const float* er = emb + v * EMBED;
    #pragma unroll 4
    for (int e = 0; e < EMBED; ++e) s = fmaf(er[e], W[e * HIDDEN + j], s);
    proj[(size_t)v * NGCOL + j * 4 + g] = s;
}

// ---- persistent LSTM: 132 blocks x 512 thr; block = 64 rows x 64 packed-cols ----
// 8 waves = 4 row-groups (rm) x 2 K-halves (kh); wave tile 16 rows x 64 pcols.
// NO global barrier: producer->consumer hflag dataflow (64 producers/rt; consumer
// wave polls its 32 kh-half producers) + 3-deep h rotation + 2-step-lagged done
// flags for WAW. A-stream: r16 staggered 6-deep pipeline (best measured).
__global__ __launch_bounds__(512, 1) void k_lstm(
        const unsigned short* __restrict__ Bp, const float* __restrict__ proj,
        const int* __restrict__ x, unsigned short* __restrict__ hb,
        float* __restrict__ out, const float* __restrict__ bcls,
        unsigned* __restrict__ bar) {
    __shared__ unsigned short ldsB[65536];   // 128 KB
    __shared__ float ldsR[4096];             // 16 KB K-split reduce

    const int b = blockIdx.x;
    const int ct = b >> 1, rt = b & 1;
    const bool gateblk = (ct < 64);
    const int tid = threadIdx.x;
    const int w = tid >> 6, lane = tid & 63;
    const int rm = w >> 1, kh = w & 1;
    const int l16 = lane & 15, lhi = lane >> 4;
    const int wrow0 = rt * 64 + rm * 16;
    const int fnA = kh * 2, fnB = kh * 2 + 1;   // FN pair this wave finalizes

    // flag layout (dword offsets in bar): hflag at 512 + rt*64 + ct (producers 0..63);
    // done at 1024 + rt*128 + ct (all 66 blocks of the rt group).
    unsigned* hflag = bar + 512;
    unsigned* done  = bar + 1024;
    unsigned* myhflag = hflag + rt * 64 + ct;
    unsigned* mydone  = done + rt * 128 + ct;

    {   // stage this block's B slice: contiguous 128 KB
        const s8v* src = (const s8v*)(Bp + (size_t)ct * 65536);
        s8v* dst = (s8v*)ldsB;
        #pragma unroll
        for (int i = 0; i < 16; ++i) dst[tid + i * 512] = src[tid + i * 512];
    }
    __syncthreads();

    const unsigned short* bb0 = ldsB + (0 * 128 + kh * 64 + lhi) * 128 + l16 * 8;
    const unsigned short* bb1 = ldsB + (1 * 128 + kh * 64 + lhi) * 128 + l16 * 8;
    const unsigned short* bb2 = ldsB + (2 * 128 + kh * 64 + lhi) * 128 + l16 * 8;
    const unsigned short* bb3 = ldsB + (3 * 128 + kh * 64 + lhi) * 128 + l16 * 8;
    float* red = ldsR + rm * 1024;   // zone per rm pair

    float creg[2][4];   // c for (fnA, fnB) x 4 rows
    #pragma unroll
    for (int c2 = 0; c2 < 2; ++c2)
        #pragma unroll
        for (int r = 0; r < 4; ++r) creg[c2][r] = 0.f;

    float bcA = 0.f, bcB = 0.f;
    int v0 = 0;
    if (!gateblk) {
        v0 = (ct - 64) * 64 + l16;
        bcA = bcls[v0 + fnA * 16];
        bcB = bcls[v0 + fnB * 16];
    }

    const int pcolA = ct * 64 + kh * 32 + l16;   // pf column base (fnA; fnB = +16)

    int xsr[4];
    if (gateblk) {
        #pragma unroll
        for (int r = 0; r < 4; ++r) xsr[r] = x[wrow0 + lhi * 4 + r];
    }

    for (int s = 0; s <= SEQ; ++s) {
        const unsigned short* hr = hb + (s % 3) * (BATCH * HIDDEN);
        unsigned short* hw = hb + ((s + 1) % 3) * (BATCH * HIDDEN);
        const bool work = gateblk ? (s < SEQ) : (s > 0);

        f4 c0 = {0,0,0,0}, c1 = {0,0,0,0}, c2 = {0,0,0,0}, c3 = {0,0,0,0};
        float pfA[4], pfB[4];
        s8v av[16];

        if (work) {
            // dataflow wait: my kh-half's 32 producers must have published h(s)
            if (s > 0) {
                const unsigned* hf = hflag + rt * 64 + kh * 32;
                const unsigned tgt = (unsigned)s;
                for (;;) {
                    unsigned v = tgt;
                    if (lane < 32)
                        v = __hip_atomic_load(hf + lane, __ATOMIC_RELAXED,
                                              __HIP_MEMORY_SCOPE_AGENT);
                    if (__ballot(v >= tgt) == ~0ull) break;
                    __builtin_amdgcn_s_sleep(1);
                }
                __builtin_amdgcn_sched_barrier(0);
            }

            const unsigned short* aptr = hr + (wrow0 + l16) * HIDDEN + kh * 512 + lhi * 8;

#define A_LOAD(I)                                                                 \
            asm volatile("global_load_dwordx4 %0, %1, off sc0 sc1"                \
                         : "=&v"(av[I]) : "v"(aptr + (I) * 32));
            A_LOAD(0) A_LOAD(1) A_LOAD(2) A_LOAD(3) A_LOAD(4) A_LOAD(5)

#define K_ITER(I, W)                                                              \
            {                                                                     \
                s8v bv0 = *(const s8v*)(bb0 + (I) * 512);                         \
                s8v bv1 = *(const s8v*)(bb1 + (I) * 512);                         \
                s8v bv2 = *(const s8v*)(bb2 + (I) * 512);                         \
                s8v bv3 = *(const s8v*)(bb3 + (I) * 512);                         \
                if ((I) + 6 < 16) { A_LOAD((I) + 6) }                             \
                asm volatile("s_waitcnt vmcnt(" #W ")" ::: "memory");             \
                __builtin_amdgcn_sched_barrier(0);                                \
                c0 = __builtin_amdgcn_mfma_f32_16x16x32_bf16(av[I], bv0, c0, 0, 0, 0); \
                c1 = __builtin_amdgcn_mfma_f32_16x16x32_bf16(av[I], bv1, c1, 0, 0, 0); \
                c2 = __builtin_amdgcn_mfma_f32_16x16x32_bf16(av[I], bv2, c2, 0, 0, 0); \
                c3 = __builtin_amdgcn_mfma_f32_16x16x32_bf16(av[I], bv3, c3, 0, 0, 0); \
            }
#define PF_LOAD(R)                                                                \
            { const float* pr = proj + (size_t)xsr[R] * NGCOL + pcolA;            \
              asm volatile("global_load_dword %0, %2, off\n\t"                    \
                           "global_load_dword %1, %3, off"                        \
                           : "=&v"(pfA[R]), "=&v"(pfB[R])                         \
                           : "v"(pr), "v"(pr + 16)); }

            if (gateblk) {
                K_ITER(0, 6) K_ITER(1, 6) K_ITER(2, 6) K_ITER(3, 6)
                K_ITER(4, 6) K_ITER(5, 6)
                PF_LOAD(0) PF_LOAD(1) PF_LOAD(2) PF_LOAD(3)
                K_ITER(6, 14) K_ITER(7, 14) K_ITER(8, 14) K_ITER(9, 14)
                K_ITER(10, 13) K_ITER(11, 12) K_ITER(12, 3) K_ITER(13, 2)
                K_ITER(14, 1) K_ITER(15, 0)
            } else {
                K_ITER(0, 6) K_ITER(1, 6) K_ITER(2, 6) K_ITER(3, 6)
                K_ITER(4, 6) K_ITER(5, 6) K_ITER(6, 6) K_ITER(7, 6)
                K_ITER(8, 6) K_ITER(9, 6) K_ITER(10, 5) K_ITER(11, 4)
                K_ITER(12, 3) K_ITER(13, 2) K_ITER(14, 1) K_ITER(15, 0)
            }

            if (gateblk && s + 1 < SEQ) {   // x prefetch for next step (untracked)
                const int* xp = x + (s + 1) * BATCH + wrow0 + lhi * 4;
#define X_LOAD(R)                                                                 \
                asm volatile("global_load_dword %0, %1, off"                      \
                             : "=&v"(xsr[R]) : "v"(xp + (R)));
                X_LOAD(0) X_LOAD(1) X_LOAD(2) X_LOAD(3)
            }
            // K-split exchange: each wave publishes the FN pair it does NOT finalize
            if (kh == 0) {
                #pragma unroll
                for (int r = 0; r < 4; ++r) {
                    red[(2 * 4 + r) * 64 + lane] = c2[r];
                    red[(3 * 4 + r) * 64 + lane] = c3[r];
                }
            } else {
                #pragma unroll
                for (int r = 0; r < 4; ++r) {
                    red[(0 * 4 + r) * 64 + lane] = c0[r];
                    red[(1 * 4 + r) * 64 + lane] = c1[r];
                }
            }
        }
        __syncthreads();
        // all waves finished consuming h(s) (A-loads in registers) -> publish done
        if (tid == 0) st_flag_wt(mydone, (unsigned)(s + 1));
        if (work) {
            f4 accA, accB;
            if (kh == 0) {
                #pragma unroll
                for (int r = 0; r < 4; ++r) {
                    accA[r] = c0[r] + red[(0 * 4 + r) * 64 + lane];
                    accB[r] = c1[r] + red[(1 * 4 + r) * 64 + lane];
                }
            } else {
                #pragma unroll
                for (int r = 0; r < 4; ++r) {
                    accA[r] = c2[r] + red[(2 * 4 + r) * 64 + lane];
                    accB[r] = c3[r] + red[(3 * 4 + r) * 64 + lane];
                }
            }
            if (gateblk) {
                // WAW guard: readers of buf[(s+2)%3] (= h(s-2) readers) must be done.
                if (s >= 2) {
                    const unsigned* dn = done + rt * 128;
                    const unsigned tgt = (unsigned)(s - 1);
                    for (;;) {
                        unsigned v1 = __hip_atomic_load(dn + lane, __ATOMIC_RELAXED,
                                                        __HIP_MEMORY_SCOPE_AGENT);
                        unsigned v2 = tgt;
                        if (lane < 2)
                            v2 = __hip_atomic_load(dn + 64 + lane, __ATOMIC_RELAXED,
                                                   __HIP_MEMORY_SCOPE_AGENT);
                        if (__ballot(v1 >= tgt && v2 >= tgt) == ~0ull) break;
                        __builtin_amdgcn_s_sleep(1);
                    }
                    __builtin_amdgcn_sched_barrier(0);
                }
                // quad-split: lane's own col is gate (lane&3); act via
                // tanh(x) = 2*sigm(2x)-1 for g-gate, sigm otherwise -> 1 exp/lane.
                const bool isg = (lane & 3) == 2;
                const int qb = lane & ~3;
                #pragma unroll
                for (int r = 0; r < 4; ++r) {
                    int row = wrow0 + lhi * 4 + r;
                    float preA = accA[r] + pfA[r];
                    float preB = accB[r] + pfB[r];
                    float xA = isg ? preA + preA : preA;
                    float xB = isg ? preB + preB : preB;
                    float sA = sigm(xA), sB = sigm(xB);
                    float actA = isg ? sA + sA - 1.f : sA;
                    float actB = isg ? sB + sB - 1.f : sB;
                    float iA = __shfl(actA, qb),     iB = __shfl(actB, qb);
                    float fA = __shfl(actA, qb | 1), fB = __shfl(actB, qb | 1);
                    float gA = __shfl(actA, qb | 2), gB = __shfl(actB, qb | 2);
                    float oA = __shfl(actA, qb | 3), oB = __shfl(actB, qb | 3);
                    float cnA = fA * creg[0][r] + iA * gA; creg[0][r] = cnA;
                    float cnB = fB * creg[1][r] + iB * gB; creg[1][r] = cnB;
                    float hvA = oA * tanh_(cnA);
                    float hvB = oB * tanh_(cnB);
                    float hnA = __shfl(hvA, lane ^ 4);
                    float hnB = __shfl(hvB, lane ^ 4);
                    unsigned packA = (unsigned)f2bf(hvA) | ((unsigned)f2bf(hnA) << 16);
                    unsigned packB = (unsigned)f2bf(hvB) | ((unsigned)f2bf(hnB) << 16);
                    unsigned packA2 = __shfl(packA, (lane & ~15) | 8);
                    unsigned packB2 = __shfl(packB, (lane & ~15) | 8);
                    if (l16 == 0) {   // one 16B store covers this wave's 8 cols of the row
                        u4v pk = {packA, packA2, packB, packB2};
                        st_b128_wt(hw + row * HIDDEN + ct * 16 + kh * 8, pk);
                    }
                }
            } else {
                float* ob = out + (size_t)(s - 1) * (BATCH * VOCAB);
#define DO_LOGIT(ACC, FN, BC)                                                     \
                _Pragma("unroll")                                                 \
                for (int r = 0; r < 4; ++r) {                                     \
                    int row = wrow0 + lhi * 4 + r;                                \
                    st_dword_wt(ob + row * VOCAB + v0 + (FN) * 16, ACC[r] + BC);  \
                }
                DO_LOGIT(accA, fnA, bcA)
                DO_LOGIT(accB, fnB, bcB)
            }
        }
        if (gateblk && s < SEQ) {
            // drain h-stores to the coherent point, then publish h(s+1) readiness
            asm volatile("s_waitcnt vmcnt(0)" ::: "memory");
            __builtin_amdgcn_sched_barrier(0);
            __syncthreads();   // all waves' stores acked
            if (tid == 0) st_flag_wt(myhflag, (unsigned)(s + 1));
        }
    }
}

extern "C" void kernel_launch(void* const* d_in, const int* in_sizes, int n_in,
                              void* d_out, int out_size, void* d_ws, size_t ws_size,
                              hipStream_t stream) {
    (void)in_sizes; (void)n_in; (void)out_size; (void)ws_size;
    const int*   x    = (const int*)d_in[0];
    const float* emb  = (const float*)d_in[1];
    const float* Wix  = (const float*)d_in[2];
    const float* Wih  = (const float*)d_in[3];
    const float* bi   = (const float*)d_in[4];
    const float* Wfx  = (const float*)d_in[5];
    const float* Wfh  = (const float*)d_in[6];
    const float* bf   = (const float*)d_in[7];
    const float* Wgx  = (const float*)d_in[8];
    const float* Wgh  = (const float*)d_in[9];
    const float* bg   = (const float*)d_in[10];
    const float* Wox  = (const float*)d_in[11];
    const float* Woh  = (const float*)d_in[12];
    const float* bo   = (const float*)d_in[13];
    const float* Wcls = (const float*)d_in[14];
    const float* bcls = (const float*)d_in[15];
    float* out = (float*)d_out;

    char* ws = (char*)d_ws;
    unsigned*       bar  = (unsigned*)ws;                         // 16 KB (hflag + done)
    unsigned short* hb   = (unsigned short*)(ws + 16384);         // 3 x 256 KB rotation
    float*          proj = (float*)(ws + 802816);                 // 2 MB
    unsigned short* Bp   = (unsigned short*)(ws + 2899968);       // 8.65 MB

    (void)hipMemsetAsync(ws, 0, 278528, stream);   // bar + h buf0 (h_0 = 0)

    k_pack <<<4096, 256, 0, stream>>>(Wih, Wfh, Wgh, Woh, Bp);
    k_packc<<<512,  256, 0, stream>>>(Wcls, Bp);
    k_proj <<<2048, 256, 0, stream>>>(emb, Wix, Wfx, Wgx, Wox, bi, bf, bg, bo, proj);
    k_lstm <<<132,  512, 0, stream>>>(Bp, proj, x, hb, out, bcls, bar);
}

// Round 20
// 3960.974 us; speedup vs baseline: 1.2698x; 1.2698x over previous
//
#include <hip/hip_runtime.h>
#include <hip/hip_bf16.h>

#define VOCAB  128
#define EMBED  256
#define HIDDEN 1024
#define SEQ    512
#define BATCH  128
#define NGCOL  4096   // 4*HIDDEN, gate-interleaved packed cols (p = 4*j + g)
#define NCOL   4224   // + VOCAB classifier cols appended

typedef short s8v __attribute__((ext_vector_type(8)));  // 8 bf16
typedef float f4  __attribute__((ext_vector_type(4)));
typedef unsigned u4v __attribute__((ext_vector_type(4)));

__device__ __forceinline__ unsigned short f2bf(float f) {
    unsigned u = __float_as_uint(f);
    u += 0x7fffu + ((u >> 16) & 1u);
    return (unsigned short)(u >> 16);
}
__device__ __forceinline__ float sigm(float x) { return 1.f / (1.f + __expf(-x)); }
__device__ __forceinline__ float tanh_(float x) {
    x = fminf(fmaxf(x, -15.f), 15.f);
    float e = __expf(2.f * x);
    return (e - 1.f) / (e + 1.f);
}

// write-through stores (sc0 sc1): ack at the coherent point, never dirty the XCD L2.
__device__ __forceinline__ void st_dword_wt(float* p, float v) {
    asm volatile("global_store_dword %0, %1, off sc0 sc1" :: "v"(p), "v"(v) : "memory");
}
__device__ __forceinline__ void st_b128_wt(unsigned short* p, u4v v) {
    asm volatile("global_store_dwordx4 %0, %1, off sc0 sc1" :: "v"(p), "v"(v) : "memory");
}
__device__ __forceinline__ void st_flag_wt(unsigned* p, unsigned v) {
    asm volatile("global_store_dword %0, %1, off sc0 sc1" :: "v"(p), "v"(v) : "memory");
}

// ---- pack gate weights, coalesced ----
__global__ void k_pack(const float* __restrict__ Wi, const float* __restrict__ Wf,
                       const float* __restrict__ Wg, const float* __restrict__ Wo,
                       unsigned short* __restrict__ Bp) {
    int idx = blockIdx.x * 256 + threadIdx.x;   // 1M threads
    int k = idx >> 10, j = idx & 1023;
    int src = k * HIDDEN + j;
    size_t base = ((size_t)(j >> 2) * 128 + (k >> 3)) * 128 + ((j & 3) << 5) + (k & 7);
    Bp[base]      = f2bf(Wi[src]);
    Bp[base + 8]  = f2bf(Wf[src]);
    Bp[base + 16] = f2bf(Wg[src]);
    Bp[base + 24] = f2bf(Wo[src]);
}

__global__ void k_packc(const float* __restrict__ Wcls, unsigned short* __restrict__ Bp) {
    int idx = blockIdx.x * 256 + threadIdx.x;   // 131072 threads: (v, k)
    int v = idx >> 10, k = idx & 1023;
    int p = NGCOL + v;
    Bp[((size_t)(p >> 4) * 128 + (k >> 3)) * 128 + (p & 15) * 8 + (k & 7)] = f2bf(Wcls[v * HIDDEN + k]);
}

__global__ void k_proj(const float* __restrict__ emb,
                       const float* __restrict__ Wix, const float* __restrict__ Wfx,
                       const float* __restrict__ Wgx, const float* __restrict__ Wox,
                       const float* __restrict__ bi,  const float* __restrict__ bf_,
                       const float* __restrict__ bg,  const float* __restrict__ bo,
                       float* __restrict__ proj) {
    int idx = blockIdx.x * 256 + threadIdx.x;   // 524288 threads: (v, g, j)
    int j = idx & 1023;
    int g = (idx >> 10) & 3;
    int v = idx >> 12;
    const float* W  = (g == 0) ? Wix : (g == 1) ? Wfx : (g == 2) ? Wgx : Wox;
    const float* bb = (g == 0) ? bi  : (g == 1) ? bf_ : (g == 2) ? bg  : bo;
    float s = bb[j];
    const float* er = emb + v * EMBED;
    #pragma unroll 4
    for (int e = 0; e < EMBED; ++e) s = fmaf(er[e], W[e * HIDDEN + j], s);
    proj[(size_t)v * NGCOL + j * 4 + g] = s;
}

// ---- persistent LSTM: 132 blocks x 512 thr; block = 64 rows x 64 packed-cols ----
// 8 waves = 4 row-groups (rm) x 2 K-halves (kh); wave tile 16 rows x 64 pcols.
// A loaded once per block, r16 staggered 6-deep pipeline (best measured).
// Barrier: two disjoint 66-block barriers (one per rt half), 6 sub-groups x 11
// + per-rt master, wave-parallel broadcast. (r18-exact: best verified 3973 us.)
__global__ __launch_bounds__(512, 1) void k_lstm(
        const unsigned short* __restrict__ Bp, const float* __restrict__ proj,
        const int* __restrict__ x, unsigned short* __restrict__ hb,
        float* __restrict__ out, const float* __restrict__ bcls,
        unsigned* __restrict__ bar) {
    __shared__ unsigned short ldsB[65536];   // 128 KB
    __shared__ float ldsR[4096];             // 16 KB K-split reduce

    const int b = blockIdx.x;
    const int ct = b >> 1, rt = b & 1;
    const bool gateblk = (ct < 64);
    const int tid = threadIdx.x;
    const int w = tid >> 6, lane = tid & 63;
    const int rm = w >> 1, kh = w & 1;
    const int l16 = lane & 15, lhi = lane >> 4;
    const int wrow0 = rt * 64 + rm * 16;
    const int fnA = kh * 2, fnB = kh * 2 + 1;   // FN pair this wave finalizes

    unsigned* goflag = bar + 256 + b * 16;

    {   // stage this block's B slice: contiguous 128 KB
        const s8v* src = (const s8v*)(Bp + (size_t)ct * 65536);
        s8v* dst = (s8v*)ldsB;
        #pragma unroll
        for (int i = 0; i < 16; ++i) dst[tid + i * 512] = src[tid + i * 512];
    }
    __syncthreads();

    const unsigned short* bb0 = ldsB + (0 * 128 + kh * 64 + lhi) * 128 + l16 * 8;
    const unsigned short* bb1 = ldsB + (1 * 128 + kh * 64 + lhi) * 128 + l16 * 8;
    const unsigned short* bb2 = ldsB + (2 * 128 + kh * 64 + lhi) * 128 + l16 * 8;
    const unsigned short* bb3 = ldsB + (3 * 128 + kh * 64 + lhi) * 128 + l16 * 8;
    float* red = ldsR + rm * 1024;   // zone per rm pair

    float creg[2][4];   // c for (fnA, fnB) x 4 rows
    #pragma unroll
    for (int c2 = 0; c2 < 2; ++c2)
        #pragma unroll
        for (int r = 0; r < 4; ++r) creg[c2][r] = 0.f;

    float bcA = 0.f, bcB = 0.f;
    int v0 = 0;
    if (!gateblk) {
        v0 = (ct - 64) * 64 + l16;
        bcA = bcls[v0 + fnA * 16];
        bcB = bcls[v0 + fnB * 16];
    }

    const int pcolA = ct * 64 + kh * 32 + l16;   // pf column base (fnA; fnB = +16)

    int xsr[4];
    if (gateblk) {
        #pragma unroll
        for (int r = 0; r < 4; ++r) xsr[r] = x[wrow0 + lhi * 4 + r];
    }

    for (int s = 0; s <= SEQ; ++s) {
        const unsigned short* hr = hb + (s & 1) * (BATCH * HIDDEN);
        unsigned short* hw = hb + ((s + 1) & 1) * (BATCH * HIDDEN);
        const bool work = gateblk ? (s < SEQ) : (s > 0);

        f4 c0 = {0,0,0,0}, c1 = {0,0,0,0}, c2 = {0,0,0,0}, c3 = {0,0,0,0};
        float pfA[4], pfB[4];
        s8v av[16];

        if (work) {
            const unsigned short* aptr = hr + (wrow0 + l16) * HIDDEN + kh * 512 + lhi * 8;

#define A_LOAD(I)                                                                 \
            asm volatile("global_load_dwordx4 %0, %1, off sc0 sc1"                \
                         : "=&v"(av[I]) : "v"(aptr + (I) * 32));
            A_LOAD(0) A_LOAD(1) A_LOAD(2) A_LOAD(3) A_LOAD(4) A_LOAD(5)

#define K_ITER(I, W)                                                              \
            {                                                                     \
                s8v bv0 = *(const s8v*)(bb0 + (I) * 512);                         \
                s8v bv1 = *(const s8v*)(bb1 + (I) * 512);                         \
                s8v bv2 = *(const s8v*)(bb2 + (I) * 512);                         \
                s8v bv3 = *(const s8v*)(bb3 + (I) * 512);                         \
                if ((I) + 6 < 16) { A_LOAD((I) + 6) }                             \
                asm volatile("s_waitcnt vmcnt(" #W ")" ::: "memory");             \
                __builtin_amdgcn_sched_barrier(0);                                \
                c0 = __builtin_amdgcn_mfma_f32_16x16x32_bf16(av[I], bv0, c0, 0, 0, 0); \
                c1 = __builtin_amdgcn_mfma_f32_16x16x32_bf16(av[I], bv1, c1, 0, 0, 0); \
                c2 = __builtin_amdgcn_mfma_f32_16x16x32_bf16(av[I], bv2, c2, 0, 0, 0); \
                c3 = __builtin_amdgcn_mfma_f32_16x16x32_bf16(av[I], bv3, c3, 0, 0, 0); \
            }
#define PF_LOAD(R)                                                                \
            { const float* pr = proj + (size_t)xsr[R] * NGCOL + pcolA;            \
              asm volatile("global_load_dword %0, %2, off\n\t"                    \
                           "global_load_dword %1, %3, off"                        \
                           : "=&v"(pfA[R]), "=&v"(pfB[R])                         \
                           : "v"(pr), "v"(pr + 16)); }

            if (gateblk) {
                // pf (8 dwords) issued after K5, force-drained at K12 (in-order audit)
                K_ITER(0, 6) K_ITER(1, 6) K_ITER(2, 6) K_ITER(3, 6)
                K_ITER(4, 6) K_ITER(5, 6)
                PF_LOAD(0) PF_LOAD(1) PF_LOAD(2) PF_LOAD(3)
                K_ITER(6, 14) K_ITER(7, 14) K_ITER(8, 14) K_ITER(9, 14)
                K_ITER(10, 13) K_ITER(11, 12) K_ITER(12, 3) K_ITER(13, 2)
                K_ITER(14, 1) K_ITER(15, 0)
            } else {
                K_ITER(0, 6) K_ITER(1, 6) K_ITER(2, 6) K_ITER(3, 6)
                K_ITER(4, 6) K_ITER(5, 6) K_ITER(6, 6) K_ITER(7, 6)
                K_ITER(8, 6) K_ITER(9, 6) K_ITER(10, 5) K_ITER(11, 4)
                K_ITER(12, 3) K_ITER(13, 2) K_ITER(14, 1) K_ITER(15, 0)
            }

            if (gateblk && s + 1 < SEQ) {   // x prefetch for next step (untracked)
                const int* xp = x + (s + 1) * BATCH + wrow0 + lhi * 4;
#define X_LOAD(R)                                                                 \
                asm volatile("global_load_dword %0, %1, off"                      \
                             : "=&v"(xsr[R]) : "v"(xp + (R)));
                X_LOAD(0) X_LOAD(1) X_LOAD(2) X_LOAD(3)
            }
            // K-split exchange: each wave publishes the FN pair it does NOT finalize
            if (kh == 0) {
                #pragma unroll
                for (int r = 0; r < 4; ++r) {
                    red[(2 * 4 + r) * 64 + lane] = c2[r];
                    red[(3 * 4 + r) * 64 + lane] = c3[r];
                }
            } else {
                #pragma unroll
                for (int r = 0; r < 4; ++r) {
                    red[(0 * 4 + r) * 64 + lane] = c0[r];
                    red[(1 * 4 + r) * 64 + lane] = c1[r];
                }
            }
        }
        __syncthreads();
        if (work) {
            f4 accA, accB;
            if (kh == 0) {
                #pragma unroll
                for (int r = 0; r < 4; ++r) {
                    accA[r] = c0[r] + red[(0 * 4 + r) * 64 + lane];
                    accB[r] = c1[r] + red[(1 * 4 + r) * 64 + lane];
                }
            } else {
                #pragma unroll
                for (int r = 0; r < 4; ++r) {
                    accA[r] = c2[r] + red[(2 * 4 + r) * 64 + lane];
                    accB[r] = c3[r] + red[(3 * 4 + r) * 64 + lane];
                }
            }
            if (gateblk) {
                // quad-split: lane's own col is gate (lane&3); act via
                // tanh(x) = 2*sigm(2x)-1 for g-gate, sigm otherwise -> 1 exp/lane.
                const bool isg = (lane & 3) == 2;
                const int qb = lane & ~3;
                #pragma unroll
                for (int r = 0; r < 4; ++r) {
                    int row = wrow0 + lhi * 4 + r;
                    float preA = accA[r] + pfA[r];
                    float preB = accB[r] + pfB[r];
                    float xA = isg ? preA + preA : preA;
                    float xB = isg ? preB + preB : preB;
                    float sA = sigm(xA), sB = sigm(xB);
                    float actA = isg ? sA + sA - 1.f : sA;
                    float actB = isg ? sB + sB - 1.f : sB;
                    float iA = __shfl(actA, qb),     iB = __shfl(actB, qb);
                    float fA = __shfl(actA, qb | 1), fB = __shfl(actB, qb | 1);
                    float gA = __shfl(actA, qb | 2), gB = __shfl(actB, qb | 2);
                    float oA = __shfl(actA, qb | 3), oB = __shfl(actB, qb | 3);
                    float cnA = fA * creg[0][r] + iA * gA; creg[0][r] = cnA;
                    float cnB = fB * creg[1][r] + iB * gB; creg[1][r] = cnB;
                    float hvA = oA * tanh_(cnA);
                    float hvB = oB * tanh_(cnB);
                    float hnA = __shfl(hvA, lane ^ 4);
                    float hnB = __shfl(hvB, lane ^ 4);
                    unsigned packA = (unsigned)f2bf(hvA) | ((unsigned)f2bf(hnA) << 16);
                    unsigned packB = (unsigned)f2bf(hvB) | ((unsigned)f2bf(hnB) << 16);
                    unsigned packA2 = __shfl(packA, (lane & ~15) | 8);
                    unsigned packB2 = __shfl(packB, (lane & ~15) | 8);
                    if (l16 == 0) {   // one 16B store covers this wave's 8 cols of the row
                        u4v pk = {packA, packA2, packB, packB2};
                        st_b128_wt(hw + row * HIDDEN + ct * 16 + kh * 8, pk);
                    }
                }
            } else {
                float* ob = out + (size_t)(s - 1) * (BATCH * VOCAB);
#define DO_LOGIT(ACC, FN, BC)                                                     \
                _Pragma("unroll")                                                 \
                for (int r = 0; r < 4; ++r) {                                     \
                    int row = wrow0 + lhi * 4 + r;                                \
                    st_dword_wt(ob + row * VOCAB + v0 + (FN) * 16, ACC[r] + BC);  \
                }
                DO_LOGIT(accA, fnA, bcA)
                DO_LOGIT(accB, fnB, bcB)
            }
        }
        if (s < SEQ) {
            asm volatile("s_waitcnt vmcnt(0)" ::: "memory");
            __builtin_amdgcn_sched_barrier(0);
            __syncthreads();
            const unsigned ep = (unsigned)(s + 1);
            if (w == 0) {
                // per-rt barrier: 66 blocks = 6 sub-groups x 11 -> rt master (fan-in 6)
                unsigned bcast = 0;
                if (lane == 0) {
                    unsigned old = __hip_atomic_fetch_add(bar + (rt * 8 + ct / 11) * 16, 1u,
                                        __ATOMIC_RELAXED, __HIP_MEMORY_SCOPE_AGENT);
                    if (old % 11u == 10u) {   // last arrival of this 11-block sub-group
                        unsigned mold = __hip_atomic_fetch_add(bar + (rt * 8 + 6) * 16, 1u,
                                            __ATOMIC_RELAXED, __HIP_MEMORY_SCOPE_AGENT);
                        if (mold == 6u * ep - 1u) bcast = 1u;
                    }
                }
                bcast = __shfl(bcast, 0);
                if (bcast) {   // wave-parallel broadcast: 66 go lines of THIS rt group
                    st_flag_wt(bar + 256 + (2 * lane + rt) * 16, ep);          // ct = lane
                    if (lane < 2)
                        st_flag_wt(bar + 256 + (2 * (64 + lane) + rt) * 16, ep); // ct = 64,65
                }
                if (lane == 0) {
                    while (__hip_atomic_load(goflag, __ATOMIC_RELAXED,
                                             __HIP_MEMORY_SCOPE_AGENT) < ep)
                        __builtin_amdgcn_s_sleep(1);
                }
            }
            __syncthreads();
        }
    }
}

extern "C" void kernel_launch(void* const* d_in, const int* in_sizes, int n_in,
                              void* d_out, int out_size, void* d_ws, size_t ws_size,
                              hipStream_t stream) {
    (void)in_sizes; (void)n_in; (void)out_size; (void)ws_size;
    const int*   x    = (const int*)d_in[0];
    const float* emb  = (const float*)d_in[1];
    const float* Wix  = (const float*)d_in[2];
    const float* Wih  = (const float*)d_in[3];
    const float* bi   = (const float*)d_in[4];
    const float* Wfx  = (const float*)d_in[5];
    const float* Wfh  = (const float*)d_in[6];
    const float* bf   = (const float*)d_in[7];
    const float* Wgx  = (const float*)d_in[8];
    const float* Wgh  = (const float*)d_in[9];
    const float* bg   = (const float*)d_in[10];
    const float* Wox  = (const float*)d_in[11];
    const float* Woh  = (const float*)d_in[12];
    const float* bo   = (const float*)d_in[13];
    const float* Wcls = (const float*)d_in[14];
    const float* bcls = (const float*)d_in[15];
    float* out = (float*)d_out;

    char* ws = (char*)d_ws;
    unsigned*       bar  = (unsigned*)ws;                         // 16 KB (ctrs + go flags)
    unsigned short* hb   = (unsigned short*)(ws + 16384);         // 2 x 256 KB ping-pong
    float*          proj = (float*)(ws + 540672);                 // 2 MB
    unsigned short* Bp   = (unsigned short*)(ws + 2637824);       // 8.65 MB

    (void)hipMemsetAsync(ws, 0, 278528, stream);   // bar + hb0 (h_0 = 0)

    k_pack <<<4096, 256, 0, stream>>>(Wih, Wfh, Wgh, Woh, Bp);
    k_packc<<<512,  256, 0, stream>>>(Wcls, Bp);
    k_proj <<<2048, 256, 0, stream>>>(emb, Wix, Wfx, Wgx, Wox, bi, bf, bg, bo, proj);
    k_lstm <<<132,  512, 0, stream>>>(Bp, proj, x, hb, out, bcls, bar);
}